// Round 15
// baseline (89.787 us; speedup 1.0000x reference)
//
#include <hip/hip_runtime.h>
#include <hip/hip_fp16.h>
#include <stdint.h>

// ---- problem constants ----
#define B_     4096
#define F_     39
#define KKPAD  133                      // 130 real kk + pad rows for depth-2 tail
#define WPANEL ((size_t)KKPAD * 1024)   // halfs per Mt panel (1 kk row = 1024 halfs = 2 KB)

typedef _Float16 f16x8  __attribute__((ext_vector_type(8)));
typedef float    f32x4  __attribute__((ext_vector_type(4)));
typedef float    f32x16 __attribute__((ext_vector_type(16)));

union FragAB { f16x8 h8; __half2 h2[4]; f32x4 f4; unsigned u[4]; __half h[8]; };

// ---------- W pre-pack: Wp[Mt][kk][ks][lane][j] fp16 (A-fragment order) ----------
// 32x32x16 A-frag: row o = Mt*32+(lane&31), k = 8*sub + j (sub = lane>>5)
// layer0 (kk<50):  seg=kk/10, kkin=kk%10 -> h = 4*kkin+2*ks+sub (scalar side),
//                  m = seg*8+j (vector side);  W0[o][h*39+m], pads h==39 / m==39 -> 0
// layer1 (kk>=50): seg=(kk-50)/10, kkin=(kk-50)%10 -> m = 4*kkin+2*ks+sub (scalar),
//                  h = seg*8+j (vector);        W1[o][h*39+m], pad m==39 -> 0
__global__ __launch_bounds__(256) void prep_w(
    const float* __restrict__ W0, const float* __restrict__ W1,
    __half* __restrict__ Wp)
{
    int idx = blockIdx.x * 256 + threadIdx.x;   // logical over 4*130*1024
    if (idx >= 4 * 130 * 1024) return;
    int j    = idx & 7;
    int lane = (idx >> 3) & 63;
    int ks   = (idx >> 9) & 1;
    int rest = idx >> 10;
    int kk   = rest % 130, Mt = rest / 130;
    int o    = Mt * 32 + (lane & 31);
    int sub  = lane >> 5;
    float v = 0.f;
    if (kk < 50) {
        int seg = kk / 10, kkin = kk - seg * 10;
        int h = 4 * kkin + 2 * ks + sub;
        int m = seg * 8 + j;
        if (h < 39 && m < 39) v = W0[o * 1521 + h * 39 + m];
    } else {
        int l = kk - 50;
        int seg = l / 10, kkin = l - seg * 10;
        int m = 4 * kkin + 2 * ks + sub;
        int h = seg * 8 + j;
        if (m < 39) v = W1[o * 2496 + h * 39 + m];
    }
    Wp[(size_t)Mt * WPANEL + ((size_t)kk * 2 + ks) * 512 + lane * 8 + j] = __float2half(v);
}

// ---------- one segment = 10 kk; depth-2 register queue, plain loads ----------
// pA/pB: per-lane pointers to this segment's base kk row (+lane*8 baked in).
__device__ __forceinline__ void seg10(
    const __half* pA, const __half* pB,
    FragAB (&An)[2][2][2],                 // [slot][mt][ks]
    const __half2 (&xsc)[2][20],
    const FragAB (&xcur)[2],
    f32x16 (&acc)[2][2])
{
#pragma unroll
    for (int kkin = 0; kkin < 10; ++kkin) {
        const int s = kkin & 1;            // compile-time slot

#pragma unroll
        for (int ks = 0; ks < 2; ++ks) {
            const int ee = 2 * kkin + ks;  // compile-time
            FragAB bfr[2];
#pragma unroll
            for (int p = 0; p < 2; ++p) {
                const __half2 xs = xsc[p][ee];
#pragma unroll
                for (int q = 0; q < 4; ++q)
                    bfr[p].h2[q] = __hmul2(xcur[p].h2[q], xs);
            }
#pragma unroll
            for (int mt = 0; mt < 2; ++mt)
#pragma unroll
                for (int p = 0; p < 2; ++p)
                    acc[mt][p] = __builtin_amdgcn_mfma_f32_32x32x16_f16(
                        An[s][mt][ks].h8, bfr[p].h8, acc[mt][p], 0, 0, 0);
        }

        // reload slot s with kk+2 (pad rows cover the tail; compiler schedules)
        An[s][0][0].f4 = *(const f32x4*)(pA + (kkin + 2) * 1024);
        An[s][0][1].f4 = *(const f32x4*)(pA + (kkin + 2) * 1024 + 512);
        An[s][1][0].f4 = *(const f32x4*)(pB + (kkin + 2) * 1024);
        An[s][1][1].f4 = *(const f32x4*)(pB + (kkin + 2) * 1024 + 512);
    }
}

// ---------- main: 512 blocks x 256 thr (4 waves); wave = 2 Mt-tiles x 4 batches ----
// mp = w&1 -> Mt pair {2mp, 2mp+1}; g = w>>1 -> batches 4g+2p+bp
__global__ __launch_bounds__(256, 2) void cin_main(
    const float* __restrict__ x, const float* __restrict__ b0,
    const float* __restrict__ b1, const __half* __restrict__ Wp,
    float* __restrict__ out)
{
    __shared__ __align__(16) __half xT[8][16][40];    // 10 KB  [bt][d][f], f=39 zero pad
    __shared__ __align__(16) __half nhT[8][16][72];   // 18.4 KB [bt][d][h]
    __shared__ float bs0[128], bs1[128];              // 1 KB bias  (total ~29.4 KB)

    const int t    = threadIdx.x;
    const int w    = t >> 6, lane = t & 63;
    const int mp   = w & 1, g = w >> 1;
    const int sub  = lane >> 5, bp = (lane >> 4) & 1, d = lane & 15;
    const int gb   = blockIdx.x * 8;

    const __half* gA = Wp + (size_t)(2 * mp) * WPANEL + lane * 8;   // panel 2mp
    const __half* gB = gA + WPANEL;                                 // panel 2mp+1

    // prologue: load kk0/kk1 into the queue (overlaps xT staging)
    FragAB An[2][2][2];
#pragma unroll
    for (int k0 = 0; k0 < 2; ++k0) {
        An[k0][0][0].f4 = *(const f32x4*)(gA + (size_t)k0 * 1024);
        An[k0][0][1].f4 = *(const f32x4*)(gA + (size_t)k0 * 1024 + 512);
        An[k0][1][0].f4 = *(const f32x4*)(gB + (size_t)k0 * 1024);
        An[k0][1][1].f4 = *(const f32x4*)(gB + (size_t)k0 * 1024 + 512);
    }

    if (t < 128) { bs0[t] = b0[t]; bs1[t] = b1[t]; }

    // xT fill: x[b][f][d] f32 -> xT[bt][d][f] fp16  (8 batches)
    for (int i = t; i < 1248; i += 256) {
        int bt = i / 156, r2 = i - bt * 156;
        int f = r2 >> 2, dq = r2 & 3;
        float4 v = *(const float4*)&x[((size_t)(gb + bt) * F_ + f) * 16 + dq * 4];
        xT[bt][dq * 4 + 0][f] = __float2half(v.x);
        xT[bt][dq * 4 + 1][f] = __float2half(v.y);
        xT[bt][dq * 4 + 2][f] = __float2half(v.z);
        xT[bt][dq * 4 + 3][f] = __float2half(v.w);
    }
    if (t < 128) xT[t >> 4][t & 15][39] = __float2half(0.f);
    __syncthreads();

    const __half* xrow0 = &xT[4 * g + bp][d][0];        // p=0 batch row
    const __half* xrow1 = &xT[4 * g + 2 + bp][d][0];    // p=1 batch row
    const unsigned psel = sub ? 0x03020302u : 0x01000100u;

    // pre-broadcast scalar regs: xsc[p][e] = half2(x[2e+sub]) — serves BOTH layers
    __half2 xsc[2][20];
#pragma unroll
    for (int a = 0; a < 5; ++a) {
        FragAB t0, t1;
        t0.f4 = *(const f32x4*)(xrow0 + a * 8);
        t1.f4 = *(const f32x4*)(xrow1 + a * 8);
#pragma unroll
        for (int b = 0; b < 4; ++b) {
            unsigned c0 = __builtin_amdgcn_perm(0u, t0.u[b], psel);
            unsigned c1 = __builtin_amdgcn_perm(0u, t1.u[b], psel);
            xsc[0][4 * a + b] = *(__half2*)&c0;
            xsc[1][4 * a + b] = *(__half2*)&c1;
        }
    }

    // acc init = b0 (C/D: col = lane&31 = bp*16+d; row = (r&3)+8*(r>>2)+4*sub)
    f32x16 acc[2][2];   // [mt][p]; row tile Mt = 2mp+mt, batch 4g+2p+bp
#pragma unroll
    for (int mt = 0; mt < 2; ++mt)
#pragma unroll
        for (int r = 0; r < 16; ++r) {
            float bv = bs0[(2 * mp + mt) * 32 + (r & 3) + 8 * (r >> 2) + 4 * sub];
            acc[mt][0][r] = bv; acc[mt][1][r] = bv;
        }

    FragAB xcur[2];

    // ---- layer 0: 5 segments (rolled); vector operand = x m-slice ----
#pragma unroll 1
    for (int s = 0; s < 5; ++s) {
        xcur[0].f4 = *(const f32x4*)(xrow0 + s * 8);
        xcur[1].f4 = *(const f32x4*)(xrow1 + s * 8);
        seg10(gA + (size_t)s * 10240, gB + (size_t)s * 10240, An, xsc, xcur, acc);
    }

    // ---- layer0 -> layer1 transition ----
    if (mp == 0) {
        // rows 0..63 -> nhT (fp16)
#pragma unroll
        for (int mt = 0; mt < 2; ++mt)
#pragma unroll
            for (int p = 0; p < 2; ++p) {
                __half* nr = &nhT[4 * g + 2 * p + bp][d][0];
#pragma unroll
                for (int rq = 0; rq < 4; ++rq) {
                    union { __half h[4]; float2 f2; } pk;
#pragma unroll
                    for (int q = 0; q < 4; ++q)
                        pk.h[q] = __float2half(fmaxf(acc[mt][p][rq * 4 + q], 0.f));
                    *(float2*)(nr + mt * 32 + 8 * rq + 4 * sub) = pk.f2;
                }
            }
    } else {
        // rows 64..127 -> direct0 (out cols 0..63): reduce over d
#pragma unroll
        for (int mt = 0; mt < 2; ++mt)
#pragma unroll
            for (int p = 0; p < 2; ++p)
#pragma unroll
                for (int rq = 0; rq < 4; ++rq) {
                    float4 s4; float* sv = (float*)&s4;
#pragma unroll
                    for (int q = 0; q < 4; ++q) {
                        float v = fmaxf(acc[mt][p][rq * 4 + q], 0.f);
                        v += __shfl_xor(v, 1); v += __shfl_xor(v, 2);
                        v += __shfl_xor(v, 4); v += __shfl_xor(v, 8);
                        sv[q] = v;
                    }
                    if (d == 0) {
                        int row = (2 + mt) * 32 + 8 * rq + 4 * sub;   // 64..127
                        int b   = gb + 4 * g + 2 * p + bp;
                        *(float4*)&out[(size_t)b * 192 + (row - 64)] = s4;
                    }
                }
    }
#pragma unroll
    for (int mt = 0; mt < 2; ++mt)
#pragma unroll
        for (int r = 0; r < 16; ++r) {
            float bv = bs1[(2 * mp + mt) * 32 + (r & 3) + 8 * (r >> 2) + 4 * sub];
            acc[mt][0][r] = bv; acc[mt][1][r] = bv;
        }
    __syncthreads();   // nhT visible to all waves

    // ---- layer 1: 8 segments (rolled); vector operand = nh h-slice ----
    const __half* nrow0 = &nhT[4 * g + bp][d][0];
    const __half* nrow1 = &nhT[4 * g + 2 + bp][d][0];
    const __half* gA1 = gA + (size_t)50 * 1024;
    const __half* gB1 = gB + (size_t)50 * 1024;
#pragma unroll 1
    for (int s = 0; s < 8; ++s) {
        xcur[0].f4 = *(const f32x4*)(nrow0 + s * 8);
        xcur[1].f4 = *(const f32x4*)(nrow1 + s * 8);
        seg10(gA1 + (size_t)s * 10240, gB1 + (size_t)s * 10240, An, xsc, xcur, acc);
    }

    // ---- final epilogue: direct1 -> out cols 64..191 ----
#pragma unroll
    for (int mt = 0; mt < 2; ++mt)
#pragma unroll
        for (int p = 0; p < 2; ++p)
#pragma unroll
            for (int rq = 0; rq < 4; ++rq) {
                float4 s4; float* sv = (float*)&s4;
#pragma unroll
                for (int q = 0; q < 4; ++q) {
                    float v = fmaxf(acc[mt][p][rq * 4 + q], 0.f);
                    v += __shfl_xor(v, 1); v += __shfl_xor(v, 2);
                    v += __shfl_xor(v, 4); v += __shfl_xor(v, 8);
                    sv[q] = v;
                }
                if (d == 0) {
                    int row = (2 * mp + mt) * 32 + 8 * rq + 4 * sub;
                    int b   = gb + 4 * g + 2 * p + bp;
                    *(float4*)&out[(size_t)b * 192 + 64 + row] = s4;
                }
            }
}

extern "C" void kernel_launch(void* const* d_in, const int* in_sizes, int n_in,
                              void* d_out, int out_size, void* d_ws, size_t ws_size,
                              hipStream_t stream) {
    const float* x  = (const float*)d_in[0];
    const float* W0 = (const float*)d_in[1];
    const float* b0 = (const float*)d_in[2];
    const float* W1 = (const float*)d_in[3];
    const float* b1 = (const float*)d_in[4];
    float* out = (float*)d_out;
    __half* Wp = (__half*)d_ws;   // 4 Mt-panels x 133 kk x 1024 halfs = 1.09 MB

    prep_w<<<(4 * 130 * 1024 + 255) / 256, 256, 0, stream>>>(W0, W1, Wp);
    cin_main<<<B_ / 8, 256, 0, stream>>>(x, b0, b1, Wp, out);
}